// Round 1
// baseline (245.852 us; speedup 1.0000x reference)
//
#include <hip/hip_runtime.h>
#include <hip/hip_bf16.h>

#define N_NODES 50000
#define N_EDGES 800000
#define IN_DIM 256
#define HEADS 4
#define HEAD_DIM 64
#define OUT_DIM 256
#define NEG_SLOPE 0.2f
#define TOTAL_E (N_EDGES + N_NODES)
#define M_PAD 50048          // 782 * 64
#define SEG_CAP 64           // fixed CSR slots per node; max degree ~48 << 63

#define GEMM_BLOCKS 782      // M_PAD / 64
#define SCAT_BLOCKS 3321     // ceil(TOTAL_E / 256)
#define MEGA_BLOCKS (GEMM_BLOCKS + SCAT_BLOCKS)

typedef float floatx4 __attribute__((ext_vector_type(4)));
typedef short shortx8 __attribute__((ext_vector_type(8)));

// ---------------- prep: W[k][n] fp32 -> Wt[n][k] bf16 (128 KB, L2-resident) ----------------
__global__ __launch_bounds__(256) void prep_wt(const float* __restrict__ W,
                                               ushort* __restrict__ Wt) {
    int t = blockIdx.x * 256 + threadIdx.x;   // 16384 threads, 4 elems each
    int n = t >> 6;
    int k = (t & 63) << 2;
    ushort4 o;
    o.x = __bfloat16_as_ushort(__float2bfloat16(W[(size_t)(k + 0) * OUT_DIM + n]));
    o.y = __bfloat16_as_ushort(__float2bfloat16(W[(size_t)(k + 1) * OUT_DIM + n]));
    o.z = __bfloat16_as_ushort(__float2bfloat16(W[(size_t)(k + 2) * OUT_DIM + n]));
    o.w = __bfloat16_as_ushort(__float2bfloat16(W[(size_t)(k + 3) * OUT_DIM + n]));
    *(ushort4*)&Wt[(size_t)n * IN_DIM + k] = o;
}

// ---------------- mega: gemm (blocks 0..781) + scatter (blocks 782..4102) ----------------
// GEMM is barrier-free / LDS-free: per-lane fragment loads directly from x (fp32->bf16
// in-register; 4 waves share rows -> L1 hits) and from pre-transposed bf16 Wt (L2).
// MFMA operand order swapped: acc = mfma(Wt-frag, x-frag, acc) so the C fragment holds
// 4 CONTIGUOUS output cols per reg -> coalesced 16B h2 stores. h2 column order is a
// fixed permutation; aggregate_v7 decodes it via col0(lane).
__global__ __launch_bounds__(256) void mega_kernel(const float* __restrict__ x,
                                                   const ushort* __restrict__ Wt,
                                                   const float* __restrict__ att_src,
                                                   const float* __restrict__ att_dst,
                                                   const int* __restrict__ e_src,
                                                   const int* __restrict__ e_dst,
                                                   int* __restrict__ cnt,
                                                   int* __restrict__ csr,
                                                   ushort* __restrict__ h2,
                                                   float* __restrict__ asrc,
                                                   float* __restrict__ adst) {
    if (blockIdx.x >= GEMM_BLOCKS) {
        // ---------------- scatter: self-allocating fixed-stride CSR ----------------
        int id = (blockIdx.x - GEMM_BLOCKS) * 256 + threadIdx.x;
        if (id < N_EDGES) {
            int s = e_src[id];
            int dn = e_dst[id];
            int pos = atomicAdd(&cnt[dn], 1);
            if (pos < SEG_CAP) csr[(dn << 6) + pos] = s;   // pos<64 always (max deg ~48)
        } else if (id < TOTAL_E) {
            int nn = id - N_EDGES;
            int pos = atomicAdd(&cnt[nn], 1);
            if (pos < SEG_CAP) csr[(nn << 6) + pos] = nn;  // self-loop
        }
        return;
    }

    // ---------------- GEMM: 64 rows x 256 cols; wave w owns head w ----------------
    const int tid = threadIdx.x;
    const int w = tid >> 6;
    const int lane = tid & 63;
    const int quad = lane >> 4;
    const int l16 = lane & 15;
    const int row0 = blockIdx.x * 64;

    floatx4 acc[4][4] = {};  // [row-tile r][col-tile c]; elem j: node=r*16+l16, col=c*16+quad*4+j

    const ushort* wtb = Wt + (size_t)(w * 64 + l16) * IN_DIM + quad * 8;

#pragma unroll 2
    for (int k0 = 0; k0 < IN_DIM; k0 += 32) {
        shortx8 bfr[4], af[4];
#pragma unroll
        for (int c = 0; c < 4; ++c)
            bfr[c] = *(const shortx8*)(wtb + (size_t)c * 16 * IN_DIM + k0);
#pragma unroll
        for (int r = 0; r < 4; ++r) {
            int gr = row0 + r * 16 + l16;
            alignas(16) ushort a8[8];
            if (gr < N_NODES) {
                const float* xp = &x[(size_t)gr * IN_DIM + k0 + quad * 8];
                float4 v0 = *(const float4*)xp;
                float4 v1 = *(const float4*)(xp + 4);
                float f[8] = {v0.x, v0.y, v0.z, v0.w, v1.x, v1.y, v1.z, v1.w};
#pragma unroll
                for (int u = 0; u < 8; ++u)
                    a8[u] = __bfloat16_as_ushort(__float2bfloat16(f[u]));
            } else {
#pragma unroll
                for (int u = 0; u < 8; ++u) a8[u] = 0;
            }
            af[r] = *(const shortx8*)a8;
        }
#pragma unroll
        for (int r = 0; r < 4; ++r)
#pragma unroll
            for (int c = 0; c < 4; ++c)
                acc[r][c] = __builtin_amdgcn_mfma_f32_16x16x32_bf16(bfr[c], af[r],
                                                                    acc[r][c], 0, 0, 0);
    }

    // ---------------- epilogue: logits + permuted-coalesced h2 store ----------------
    // lane holds cols {c*16 + quad*4 + j} of node r*16+l16 -> store at slot quad*16+c*4+j.
    float as_cj[16], ad_cj[16];
#pragma unroll
    for (int c = 0; c < 4; ++c)
#pragma unroll
        for (int j = 0; j < 4; ++j) {
            int col = w * 64 + c * 16 + quad * 4 + j;
            as_cj[c * 4 + j] = att_src[col];
            ad_cj[c * 4 + j] = att_dst[col];
        }
#pragma unroll
    for (int r = 0; r < 4; ++r) {
        float s = 0.f, d = 0.f;
        alignas(16) ushort o16[16];
#pragma unroll
        for (int c = 0; c < 4; ++c)
#pragma unroll
            for (int j = 0; j < 4; ++j) {
                float v = acc[r][c][j];
                s = fmaf(v, as_cj[c * 4 + j], s);
                d = fmaf(v, ad_cj[c * 4 + j], d);
                o16[c * 4 + j] = __bfloat16_as_ushort(__float2bfloat16(v));
            }
        // reduce across the 4 quads (lanes differing in bits 4,5) -> full 64-col dot
        s += __shfl_xor(s, 16);
        s += __shfl_xor(s, 32);
        d += __shfl_xor(d, 16);
        d += __shfl_xor(d, 32);
        int gr = row0 + r * 16 + l16;
        if (quad == 0 && gr < N_NODES) {
            asrc[gr * HEADS + w] = s;
            adst[gr * HEADS + w] = d;
        }
        // h2 store: 32B contiguous per lane (pad rows < M_PAD, harmless zeros)
        ushort* hp = h2 + (size_t)gr * OUT_DIM + w * 64 + quad * 16;
        *(uint4*)hp = *(const uint4*)&o16[0];
        *(uint4*)(hp + 8) = *(const uint4*)&o16[8];
    }
}

// ---------------- aggregate v8: one wave/node, single pass, masked tail batch ----------------
// block 256 = 4 nodes. Lane reads h2 slots [lane*4, lane*4+4); with the permuted h2
// layout these are cols col0..col0+3 where col0 = (lane>>4)*64 + (lane&3)*16 + ((lane>>2)&3)*4.
// head = lane>>4 (unchanged). den fused into gather loop.
__global__ __launch_bounds__(256) void aggregate_v8(const uint2* __restrict__ h2,
                                                    const float* __restrict__ a_src,
                                                    const float* __restrict__ a_dst,
                                                    const int* __restrict__ cnt,
                                                    const int* __restrict__ csr,
                                                    const float* __restrict__ bias,
                                                    float* __restrict__ out) {
    int n = blockIdx.x * 4 + (threadIdx.x >> 6);
    if (n >= N_NODES) return;
    int lane = threadIdx.x & 63;
    int h = lane >> 4;
    int col0 = ((lane >> 4) << 6) + ((lane & 3) << 4) + (((lane >> 2) & 3) << 2);
    int beg = n << 6;
    int cn = min(cnt[n], SEG_CAP);  // includes self-loop
    int nfull = cn >> 3, rem = cn & 7;
    float adv = a_dst[n * HEADS + h];

    float den = 0.f;
    float acc0 = 0.f, acc1 = 0.f, acc2 = 0.f, acc3 = 0.f;
    for (int b = 0; b < nfull; ++b) {
        int i = beg + b * 8;
        int4 sa = *(const int4*)&csr[i];
        int4 sb = *(const int4*)&csr[i + 4];
        int ss[8] = {sa.x, sa.y, sa.z, sa.w, sb.x, sb.y, sb.z, sb.w};
        float asv[8];
        uint2 hv[8];
#pragma unroll
        for (int u = 0; u < 8; ++u) {
            asv[u] = a_src[ss[u] * HEADS + h];
            hv[u] = h2[(size_t)ss[u] * 64 + lane];
        }
#pragma unroll
        for (int u = 0; u < 8; ++u) {
            float e = asv[u] + adv;
            e = fmaxf(e, NEG_SLOPE * e);
            float p = __expf(e);
            den += p;
            acc0 = fmaf(p, __uint_as_float(hv[u].x << 16), acc0);
            acc1 = fmaf(p, __uint_as_float(hv[u].x & 0xffff0000u), acc1);
            acc2 = fmaf(p, __uint_as_float(hv[u].y << 16), acc2);
            acc3 = fmaf(p, __uint_as_float(hv[u].y & 0xffff0000u), acc3);
        }
    }
    if (rem) {
        int i = beg + nfull * 8;
        int4 sa = *(const int4*)&csr[i];
        int4 sb = *(const int4*)&csr[i + 4];
        int ss[8] = {sa.x, sa.y, sa.z, sa.w, sb.x, sb.y, sb.z, sb.w};
        float asv[8];
        uint2 hv[8];
#pragma unroll
        for (int u = 0; u < 8; ++u) {
            int s = (u < rem) ? ss[u] : 0;       // clamp garbage slots to valid index
            asv[u] = a_src[s * HEADS + h];
            hv[u] = h2[(size_t)s * 64 + lane];
        }
#pragma unroll
        for (int u = 0; u < 8; ++u) {
            float e = asv[u] + adv;
            e = fmaxf(e, NEG_SLOPE * e);
            float p = (u < rem) ? __expf(e) : 0.f;
            den += p;
            acc0 = fmaf(p, __uint_as_float(hv[u].x << 16), acc0);
            acc1 = fmaf(p, __uint_as_float(hv[u].x & 0xffff0000u), acc1);
            acc2 = fmaf(p, __uint_as_float(hv[u].y << 16), acc2);
            acc3 = fmaf(p, __uint_as_float(hv[u].y & 0xffff0000u), acc3);
        }
    }
    float idv = 1.0f / den;
    float4 b = *(const float4*)&bias[col0];
    float4 o = make_float4(acc0 * idv + b.x, acc1 * idv + b.y,
                           acc2 * idv + b.z, acc3 * idv + b.w);
    *(float4*)&out[(size_t)n * OUT_DIM + col0] = o;
}

extern "C" void kernel_launch(void* const* d_in, const int* in_sizes, int n_in,
                              void* d_out, int out_size, void* d_ws, size_t ws_size,
                              hipStream_t stream) {
    const float* x = (const float*)d_in[0];
    const int* ei = (const int*)d_in[1];
    const float* W = (const float*)d_in[2];
    const float* att_src = (const float*)d_in[3];
    const float* att_dst = (const float*)d_in[4];
    const float* bias = (const float*)d_in[5];
    float* out = (float*)d_out;

    const int* e_src = ei;
    const int* e_dst = ei + N_EDGES;

    char* p = (char*)d_ws;
    auto alloc = [&](size_t bytes) {
        void* r = (void*)p;
        p += (bytes + 255) & ~(size_t)255;
        return r;
    };
    ushort* h2   = (ushort*)alloc((size_t)M_PAD * OUT_DIM * 2);
    float* asrc  = (float*)alloc((size_t)N_NODES * HEADS * 4);
    float* adst  = (float*)alloc((size_t)N_NODES * HEADS * 4);
    int* cnt     = (int*)alloc((size_t)N_NODES * 4);
    int* csr     = (int*)alloc((size_t)N_NODES * SEG_CAP * 4);
    ushort* Wt   = (ushort*)alloc((size_t)IN_DIM * OUT_DIM * 2);

    hipMemsetAsync(cnt, 0, (size_t)N_NODES * 4, stream);
    prep_wt<<<64, 256, 0, stream>>>(W, Wt);
    mega_kernel<<<MEGA_BLOCKS, 256, 0, stream>>>(x, Wt, att_src, att_dst, e_src, e_dst,
                                                 cnt, csr, h2, asrc, adst);
    aggregate_v8<<<(N_NODES + 3) / 4, 256, 0, stream>>>((const uint2*)h2, asrc, adst,
                                                        cnt, csr, bias, out);
}

// Round 2
// 226.404 us; speedup vs baseline: 1.0859x; 1.0859x over previous
//
#include <hip/hip_runtime.h>
#include <hip/hip_bf16.h>

#define N_NODES 50000
#define N_EDGES 800000
#define IN_DIM 256
#define HEADS 4
#define HEAD_DIM 64
#define OUT_DIM 256
#define NEG_SLOPE 0.2f
#define TOTAL_E (N_EDGES + N_NODES)
#define M_PAD 50048          // 782 * 64
#define SEG_CAP 64           // fixed CSR slots per node; max degree ~48 << 63

#define GEMM_BLOCKS 782      // M_PAD / 64
#define SCAT_BLOCKS 3321     // ceil(TOTAL_E / 256)
#define MEGA_BLOCKS (GEMM_BLOCKS + SCAT_BLOCKS)

typedef float floatx4 __attribute__((ext_vector_type(4)));
typedef short shortx8 __attribute__((ext_vector_type(8)));

// ---------------- prep: Wt bf16 transpose + cnt zero (replaces memset dispatch) ----------
__global__ __launch_bounds__(256) void prep(const float* __restrict__ W,
                                            ushort* __restrict__ Wt,
                                            int* __restrict__ cnt) {
    int b = blockIdx.x;
    if (b < 64) {
        // W[k][n] fp32 -> Wt[n][k] bf16 (128 KB, L2-resident)
        int t = b * 256 + threadIdx.x;   // 16384 threads, 4 elems each
        int n = t >> 6;
        int k = (t & 63) << 2;
        ushort4 o;
        o.x = __bfloat16_as_ushort(__float2bfloat16(W[(size_t)(k + 0) * OUT_DIM + n]));
        o.y = __bfloat16_as_ushort(__float2bfloat16(W[(size_t)(k + 1) * OUT_DIM + n]));
        o.z = __bfloat16_as_ushort(__float2bfloat16(W[(size_t)(k + 2) * OUT_DIM + n]));
        o.w = __bfloat16_as_ushort(__float2bfloat16(W[(size_t)(k + 3) * OUT_DIM + n]));
        *(ushort4*)&Wt[(size_t)n * IN_DIM + k] = o;
    } else {
        int t = (b - 64) * 256 + threadIdx.x;
        if (t < 12500) ((int4*)cnt)[t] = make_int4(0, 0, 0, 0);  // 12500*4 = 50000 ints
    }
}
#define PREP_BLOCKS 113      // 64 Wt + 49 cnt

// ---------------- mega: gemm (blocks 0..781) + scatter (blocks 782..4102) ----------------
// GEMM: A staged fp32 via global_load_lds (async DMA, double-buffered, ONE barrier per
// k-step). Linear LDS dest (gload_lds requirement); bank conflicts broken by XOR-swizzling
// the per-lane GLOBAL source (chunk ^= row&7) so the read side can unswizzle (m173 pattern).
// B fragments per-lane from pre-transposed bf16 Wt (L2-resident). MFMA operand order
// swapped: acc = mfma(Wt-frag, x-frag, acc) -> C fragment holds 4 CONTIGUOUS output cols
// -> coalesced 16B h2 stores. aggregate decodes the fixed column permutation via col0(lane).
__global__ __launch_bounds__(256) void mega_kernel(const float* __restrict__ x,
                                                   const ushort* __restrict__ Wt,
                                                   const float* __restrict__ att_src,
                                                   const float* __restrict__ att_dst,
                                                   const int* __restrict__ e_src,
                                                   const int* __restrict__ e_dst,
                                                   int* __restrict__ cnt,
                                                   int* __restrict__ csr,
                                                   ushort* __restrict__ h2,
                                                   float* __restrict__ asrc,
                                                   float* __restrict__ adst) {
    __shared__ float A_lds[2][64 * 32];   // 2 x 8 KB, [row][32 k floats], 16B-chunk swizzled

    if (blockIdx.x >= GEMM_BLOCKS) {
        // ---------------- scatter: self-allocating fixed-stride CSR ----------------
        int id = (blockIdx.x - GEMM_BLOCKS) * 256 + threadIdx.x;
        if (id < N_EDGES) {
            int s = e_src[id];
            int dn = e_dst[id];
            int pos = atomicAdd(&cnt[dn], 1);
            if (pos < SEG_CAP) csr[(dn << 6) + pos] = s;   // pos<64 always (max deg ~48)
        } else if (id < TOTAL_E) {
            int nn = id - N_EDGES;
            int pos = atomicAdd(&cnt[nn], 1);
            if (pos < SEG_CAP) csr[(nn << 6) + pos] = nn;  // self-loop
        }
        return;
    }

    const int tid = threadIdx.x;
    const int w = tid >> 6;
    const int lane = tid & 63;
    const int quad = lane >> 4;
    const int l16 = lane & 15;
    const int row0 = blockIdx.x * 64;

    // stage A-tile (64 rows x 32 fp32) into LDS buf via async DMA: 512 slots of 16B,
    // 2 issues x 256 threads. slot s -> (row=s>>3, chunk_lin=s&7); data placed there is
    // global chunk (chunk_lin ^ (row&7)) -> read side applies the same XOR.
    auto stage = [&](int buf, int k0) {
#pragma unroll
        for (int i = 0; i < 2; ++i) {
            int s = i * 256 + tid;
            int row = s >> 3;
            int cg = (s & 7) ^ (row & 7);
            int gr = row0 + row;
            if (gr > N_NODES - 1) gr = N_NODES - 1;   // clamp: pad rows read valid mem
            const float* src = &x[(size_t)gr * IN_DIM + k0 + cg * 4];
            __builtin_amdgcn_global_load_lds(
                (const __attribute__((address_space(1))) unsigned int*)src,
                (__attribute__((address_space(3))) unsigned int*)&A_lds[buf][s * 4],
                16, 0, 0);
        }
    };

    floatx4 acc[4][4] = {};  // [r][c]; elem j: node=row0+r*16+l16, col=c*16+quad*4+j
    const ushort* wtb = Wt + (size_t)(w * 64 + l16) * IN_DIM + quad * 8;

    stage(0, 0);
    __syncthreads();
#pragma unroll 2
    for (int t = 0; t < 8; ++t) {
        int cur = t & 1;
        if (t < 7) stage(cur ^ 1, (t + 1) * 32);   // prefetch flies under this iteration
        int k0 = t * 32;
        shortx8 bfr[4], af[4];
#pragma unroll
        for (int c = 0; c < 4; ++c)
            bfr[c] = *(const shortx8*)(wtb + (size_t)c * 16 * IN_DIM + k0);
#pragma unroll
        for (int r = 0; r < 4; ++r) {
            int row = r * 16 + l16;
            const float* Ab = &A_lds[cur][row * 32];
            int sw = row & 7;
            float4 f0 = *(const float4*)&Ab[((2 * quad) ^ sw) * 4];
            float4 f1 = *(const float4*)&Ab[((2 * quad + 1) ^ sw) * 4];
            float f[8] = {f0.x, f0.y, f0.z, f0.w, f1.x, f1.y, f1.z, f1.w};
            alignas(16) ushort a8[8];
#pragma unroll
            for (int u = 0; u < 8; ++u)
                a8[u] = __bfloat16_as_ushort(__float2bfloat16(f[u]));
            af[r] = *(const shortx8*)a8;
        }
#pragma unroll
        for (int r = 0; r < 4; ++r)
#pragma unroll
            for (int c = 0; c < 4; ++c)
                acc[r][c] = __builtin_amdgcn_mfma_f32_16x16x32_bf16(bfr[c], af[r],
                                                                    acc[r][c], 0, 0, 0);
        __syncthreads();   // drains prefetch vmem + orders LDS reuse (one barrier/step)
    }

    // ---------------- epilogue: logits + permuted-coalesced h2 store ----------------
    float as_cj[16], ad_cj[16];
#pragma unroll
    for (int c = 0; c < 4; ++c)
#pragma unroll
        for (int j = 0; j < 4; ++j) {
            int col = w * 64 + c * 16 + quad * 4 + j;
            as_cj[c * 4 + j] = att_src[col];
            ad_cj[c * 4 + j] = att_dst[col];
        }
#pragma unroll
    for (int r = 0; r < 4; ++r) {
        float s = 0.f, d = 0.f;
        alignas(16) ushort o16[16];
#pragma unroll
        for (int c = 0; c < 4; ++c)
#pragma unroll
            for (int j = 0; j < 4; ++j) {
                float v = acc[r][c][j];
                s = fmaf(v, as_cj[c * 4 + j], s);
                d = fmaf(v, ad_cj[c * 4 + j], d);
                o16[c * 4 + j] = __bfloat16_as_ushort(__float2bfloat16(v));
            }
        s += __shfl_xor(s, 16);
        s += __shfl_xor(s, 32);
        d += __shfl_xor(d, 16);
        d += __shfl_xor(d, 32);
        int gr = row0 + r * 16 + l16;
        if (quad == 0 && gr < N_NODES) {
            asrc[gr * HEADS + w] = s;
            adst[gr * HEADS + w] = d;
        }
        ushort* hp = h2 + (size_t)gr * OUT_DIM + w * 64 + quad * 16;
        *(uint4*)hp = *(const uint4*)&o16[0];
        *(uint4*)(hp + 8) = *(const uint4*)&o16[8];
    }
}

// ---------------- aggregate v8: one wave/node, single pass, masked tail batch ----------------
// block 256 = 4 nodes. Lane reads h2 slots [lane*4, lane*4+4); with the permuted h2
// layout these are cols col0..col0+3, col0 = (lane>>4)*64 + (lane&3)*16 + ((lane>>2)&3)*4.
__global__ __launch_bounds__(256) void aggregate_v8(const uint2* __restrict__ h2,
                                                    const float* __restrict__ a_src,
                                                    const float* __restrict__ a_dst,
                                                    const int* __restrict__ cnt,
                                                    const int* __restrict__ csr,
                                                    const float* __restrict__ bias,
                                                    float* __restrict__ out) {
    int n = blockIdx.x * 4 + (threadIdx.x >> 6);
    if (n >= N_NODES) return;
    int lane = threadIdx.x & 63;
    int h = lane >> 4;
    int col0 = ((lane >> 4) << 6) + ((lane & 3) << 4) + (((lane >> 2) & 3) << 2);
    int beg = n << 6;
    int cn = min(cnt[n], SEG_CAP);  // includes self-loop
    int nfull = cn >> 3, rem = cn & 7;
    float adv = a_dst[n * HEADS + h];

    float den = 0.f;
    float acc0 = 0.f, acc1 = 0.f, acc2 = 0.f, acc3 = 0.f;
    for (int b = 0; b < nfull; ++b) {
        int i = beg + b * 8;
        int4 sa = *(const int4*)&csr[i];
        int4 sb = *(const int4*)&csr[i + 4];
        int ss[8] = {sa.x, sa.y, sa.z, sa.w, sb.x, sb.y, sb.z, sb.w};
        float asv[8];
        uint2 hv[8];
#pragma unroll
        for (int u = 0; u < 8; ++u) {
            asv[u] = a_src[ss[u] * HEADS + h];
            hv[u] = h2[(size_t)ss[u] * 64 + lane];
        }
#pragma unroll
        for (int u = 0; u < 8; ++u) {
            float e = asv[u] + adv;
            e = fmaxf(e, NEG_SLOPE * e);
            float p = __expf(e);
            den += p;
            acc0 = fmaf(p, __uint_as_float(hv[u].x << 16), acc0);
            acc1 = fmaf(p, __uint_as_float(hv[u].x & 0xffff0000u), acc1);
            acc2 = fmaf(p, __uint_as_float(hv[u].y << 16), acc2);
            acc3 = fmaf(p, __uint_as_float(hv[u].y & 0xffff0000u), acc3);
        }
    }
    if (rem) {
        int i = beg + nfull * 8;
        int4 sa = *(const int4*)&csr[i];
        int4 sb = *(const int4*)&csr[i + 4];
        int ss[8] = {sa.x, sa.y, sa.z, sa.w, sb.x, sb.y, sb.z, sb.w};
        float asv[8];
        uint2 hv[8];
#pragma unroll
        for (int u = 0; u < 8; ++u) {
            int s = (u < rem) ? ss[u] : 0;       // clamp garbage slots to valid index
            asv[u] = a_src[s * HEADS + h];
            hv[u] = h2[(size_t)s * 64 + lane];
        }
#pragma unroll
        for (int u = 0; u < 8; ++u) {
            float e = asv[u] + adv;
            e = fmaxf(e, NEG_SLOPE * e);
            float p = (u < rem) ? __expf(e) : 0.f;
            den += p;
            acc0 = fmaf(p, __uint_as_float(hv[u].x << 16), acc0);
            acc1 = fmaf(p, __uint_as_float(hv[u].x & 0xffff0000u), acc1);
            acc2 = fmaf(p, __uint_as_float(hv[u].y << 16), acc2);
            acc3 = fmaf(p, __uint_as_float(hv[u].y & 0xffff0000u), acc3);
        }
    }
    float idv = 1.0f / den;
    float4 b = *(const float4*)&bias[col0];
    float4 o = make_float4(acc0 * idv + b.x, acc1 * idv + b.y,
                           acc2 * idv + b.z, acc3 * idv + b.w);
    *(float4*)&out[(size_t)n * OUT_DIM + col0] = o;
}

extern "C" void kernel_launch(void* const* d_in, const int* in_sizes, int n_in,
                              void* d_out, int out_size, void* d_ws, size_t ws_size,
                              hipStream_t stream) {
    const float* x = (const float*)d_in[0];
    const int* ei = (const int*)d_in[1];
    const float* W = (const float*)d_in[2];
    const float* att_src = (const float*)d_in[3];
    const float* att_dst = (const float*)d_in[4];
    const float* bias = (const float*)d_in[5];
    float* out = (float*)d_out;

    const int* e_src = ei;
    const int* e_dst = ei + N_EDGES;

    char* p = (char*)d_ws;
    auto alloc = [&](size_t bytes) {
        void* r = (void*)p;
        p += (bytes + 255) & ~(size_t)255;
        return r;
    };
    ushort* h2   = (ushort*)alloc((size_t)M_PAD * OUT_DIM * 2);
    float* asrc  = (float*)alloc((size_t)N_NODES * HEADS * 4);
    float* adst  = (float*)alloc((size_t)N_NODES * HEADS * 4);
    int* cnt     = (int*)alloc((size_t)N_NODES * 4);
    int* csr     = (int*)alloc((size_t)N_NODES * SEG_CAP * 4);
    ushort* Wt   = (ushort*)alloc((size_t)IN_DIM * OUT_DIM * 2);

    prep<<<PREP_BLOCKS, 256, 0, stream>>>(W, Wt, cnt);
    mega_kernel<<<MEGA_BLOCKS, 256, 0, stream>>>(x, Wt, att_src, att_dst, e_src, e_dst,
                                                 cnt, csr, h2, asrc, adst);
    aggregate_v8<<<(N_NODES + 3) / 4, 256, 0, stream>>>((const uint2*)h2, asrc, adst,
                                                        cnt, csr, bias, out);
}